// Round 5
// baseline (642.623 us; speedup 1.0000x reference)
//
#include <hip/hip_runtime.h>
#include <cstddef>

#define N_NODES 12288
#define SIG     2048
#define C1N     16
#define L1N     1024
#define C2N     32
#define L2N     512
#define F0      64
#define F1      128
#define NEDGE   196608
#define NGRAPH  1024

#define C1W     272      // u16 row stride of c1 planes (264 slots + pad)

typedef float f32x4 __attribute__((ext_vector_type(4)));
typedef short s16x8 __attribute__((ext_vector_type(8)));

__device__ __forceinline__ unsigned short bf16_rtn(float f) {
    union { float f; unsigned u; } c; c.f = f;
    unsigned r = c.u + 0x7FFFu + ((c.u >> 16) & 1u);
    return (unsigned short)(r >> 16);
}
__device__ __forceinline__ float bf16_to_f(unsigned short h) {
    union { unsigned u; float f; } c; c.u = ((unsigned)h) << 16;
    return c.f;
}

// ---------------------------------------------------------------- encoder
// one block (256 threads = 4 waves) per node.
// conv1: fp32 VALU -> two LDS u16 planes (bf16 hi / bf16 lo), pair-packed b32 writes.
// conv2: split-bf16 MFMA GEMM, K padded 16ch x 8taps = 128 (taps 5..7 have ZERO
//   weights so the B values there are don't-care -> a lane's 8 k-elems are one
//   channel's 8 CONSECUTIVE slots 2q..2q+7 => four ds_read_b32 per fragment).
//   C ~= Whi*Bhi + Whi*Blo + Wlo*Bhi (lo*lo dropped, rel err ~2^-17).
// mfma_f32_16x16x32_bf16 (m89/m91): A row=l&15,k=(l>>4)*8+j; B col=l&15,same k;
//   C/D col=l&15, row=(l>>4)*4+reg.
// Round-2 lesson: no min-waves hint (launch_bounds(256,4) caused acc spills).
// Round-4 lesson: B-slot index bug (+128*nt for +64*nt) passed validation at
//   0.0024 absmax because the position-mean washed it out — fixed here by
//   construction (q enters the address once, as 4*q bytes).
__global__ __launch_bounds__(256) void k_encoder(
    const float* __restrict__ x_raw,
    const float* __restrict__ conv1_w, const float* __restrict__ conv1_b,
    const float* __restrict__ conv2_w, const float* __restrict__ conv2_b,
    const float* __restrict__ lin_w,   const float* __restrict__ lin_b,
    float* __restrict__ h0)
{
    __shared__ float xs[2080];                 // x[i] at xs[8+i], zero pad both sides+tail
    __shared__ unsigned short c1p[2][C1N][C1W];// [plane hi/lo][ic][slot]
    __shared__ float w1s[C1N * 8];             // conv1: 7 weights + bias
    __shared__ float wmsum[4][C2N];
    __shared__ float mean_s[C2N];

    const int tid  = threadIdx.x;
    const int node = blockIdx.x;
    const int lane = tid & 63;
    const int wv   = tid >> 6;
    const int colL = lane & 15;                // MFMA col within 16-tile
    const int hi8  = lane >> 4;                // k-subgroup / C-row-group

    // ---- stage xs, w1s
    {
        const float* xrow = x_raw + (size_t)node * SIG;
        for (int i = tid; i < 2080; i += 256) {
            int xi = i - 8;
            xs[i] = (xi >= 0 && xi < SIG) ? xrow[xi] : 0.f;
        }
    }
    for (int i = tid; i < C1N * 8; i += 256) {
        int ic = i >> 3, t = i & 7;
        w1s[i] = (t < 7) ? conv1_w[ic * 7 + t] : conv1_b[ic];
    }

    // ---- A fragments: W hi/lo, 2 m-tiles x 4 k-tiles (K = 16*8 = 128, taps 5..7 zero)
    s16x8 whi[2][4], wlo[2][4];
    #pragma unroll
    for (int mt = 0; mt < 2; ++mt) {
        const int oc = mt * 16 + colL;
        #pragma unroll
        for (int kt = 0; kt < 4; ++kt) {
            const int ic = kt * 4 + hi8;
            #pragma unroll
            for (int j = 0; j < 8; ++j) {
                float w = (j < 5) ? conv2_w[oc * 80 + ic * 5 + j] : 0.f;
                unsigned short h = bf16_rtn(w);
                whi[mt][kt][j] = (short)h;
                wlo[mt][kt][j] = (short)bf16_rtn(w - bf16_to_f(h));
            }
        }
    }
    float bias[2][4];
    #pragma unroll
    for (int mt = 0; mt < 2; ++mt)
        #pragma unroll
        for (int r = 0; r < 4; ++r)
            bias[mt][r] = conv2_b[mt * 16 + hi8 * 4 + r];

    float msumr[2][4];
    #pragma unroll
    for (int mt = 0; mt < 2; ++mt)
        #pragma unroll
        for (int r = 0; r < 4; ++r) msumr[mt][r] = 0.f;

    __syncthreads();

    // ---- 4 phases of 128 conv2 output positions each
    #pragma unroll 1
    for (int phase = 0; phase < 4; ++phase) {
        const int P0 = 256 * phase;            // c1 position of slot s=2 (slot s holds P0-2+s)

        // conv1 -> planes, two adjacent slots per iteration, one b32 write per plane
        for (int i = tid; i < C1N * 132; i += 256) {
            int ic = i / 132;
            int m  = i - ic * 132;             // pair index: slots 2m, 2m+1
            int P  = P0 - 2 + 2 * m;
            const float* w  = &w1s[ic << 3];
            const float* xp = &xs[2 * P + 5];  // valid: 2P+5 >= 1, max read 2069 < 2080
            float xv[9];
            #pragma unroll
            for (int t = 0; t < 9; ++t) xv[t] = xp[t];
            float a0 = w[7], a1 = w[7];
            #pragma unroll
            for (int t = 0; t < 7; ++t) {
                a0 = fmaf(xv[t],     w[t], a0);
                a1 = fmaf(xv[t + 2], w[t], a1);
            }
            float v0 = ((unsigned)P       < (unsigned)L1N) ? fmaxf(a0, 0.f) : 0.f;
            float v1 = ((unsigned)(P + 1) < (unsigned)L1N) ? fmaxf(a1, 0.f) : 0.f;
            unsigned short h0v = bf16_rtn(v0), h1v = bf16_rtn(v1);
            unsigned short l0v = bf16_rtn(v0 - bf16_to_f(h0v));
            unsigned short l1v = bf16_rtn(v1 - bf16_to_f(h1v));
            *(unsigned*)&c1p[0][ic][2 * m] = (unsigned)h0v | ((unsigned)h1v << 16);
            *(unsigned*)&c1p[1][ic][2 * m] = (unsigned)l0v | ((unsigned)l1v << 16);
        }
        __syncthreads();

        // conv2 MFMA: wave wv covers positions 32wv..32wv+31 (n-tiles nt=0,1)
        f32x4 acc[2][2];   // [nt][mt]
        #pragma unroll
        for (int nt = 0; nt < 2; ++nt)
            #pragma unroll
            for (int mt = 0; mt < 2; ++mt) {
                acc[nt][mt][0] = bias[mt][0]; acc[nt][mt][1] = bias[mt][1];
                acc[nt][mt][2] = bias[mt][2]; acc[nt][mt][3] = bias[mt][3];
            }

        #pragma unroll
        for (int kt = 0; kt < 4; ++kt) {
            const int ic = kt * 4 + hi8;
            const unsigned* rh = (const unsigned*)&c1p[0][ic][0];
            const unsigned* rl = (const unsigned*)&c1p[1][ic][0];
            #pragma unroll
            for (int nt = 0; nt < 2; ++nt) {
                const int q = 32 * wv + 16 * nt + colL;   // q_local; B slots 2q..2q+7
                union { unsigned u[4]; s16x8 v; } BH, BL;
                #pragma unroll
                for (int u = 0; u < 4; ++u) {
                    BH.u[u] = rh[q + u];                  // u16 pair (2q+2u, 2q+2u+1)
                    BL.u[u] = rl[q + u];
                }
                #pragma unroll
                for (int mt = 0; mt < 2; ++mt) {
                    acc[nt][mt] = __builtin_amdgcn_mfma_f32_16x16x32_bf16(whi[mt][kt], BH.v, acc[nt][mt], 0, 0, 0);
                    acc[nt][mt] = __builtin_amdgcn_mfma_f32_16x16x32_bf16(whi[mt][kt], BL.v, acc[nt][mt], 0, 0, 0);
                    acc[nt][mt] = __builtin_amdgcn_mfma_f32_16x16x32_bf16(wlo[mt][kt], BH.v, acc[nt][mt], 0, 0, 0);
                }
            }
        }

        // relu + position-sum
        #pragma unroll
        for (int nt = 0; nt < 2; ++nt)
            #pragma unroll
            for (int mt = 0; mt < 2; ++mt)
                #pragma unroll
                for (int r = 0; r < 4; ++r)
                    msumr[mt][r] += fmaxf(acc[nt][mt][r], 0.f);

        __syncthreads();   // before next phase overwrites c1p
    }

    // ---- reduce over the 16 columns within each 16-lane group
    #pragma unroll
    for (int mt = 0; mt < 2; ++mt)
        #pragma unroll
        for (int r = 0; r < 4; ++r) {
            float s = msumr[mt][r];
            s += __shfl_xor(s, 1);
            s += __shfl_xor(s, 2);
            s += __shfl_xor(s, 4);
            s += __shfl_xor(s, 8);
            msumr[mt][r] = s;
        }
    if (colL == 0) {
        #pragma unroll
        for (int mt = 0; mt < 2; ++mt)
            #pragma unroll
            for (int r = 0; r < 4; ++r)
                wmsum[wv][mt * 16 + hi8 * 4 + r] = msumr[mt][r];
    }
    __syncthreads();

    if (tid < C2N) {
        float s = wmsum[0][tid] + wmsum[1][tid] + wmsum[2][tid] + wmsum[3][tid];
        mean_s[tid] = s * (1.f / 512.f);
    }
    __syncthreads();

    // ---- linear 32 -> 64
    if (tid < F0) {
        float a = lin_b[tid];
        #pragma unroll
        for (int ic = 0; ic < C2N; ++ic)
            a = fmaf(mean_s[ic], lin_w[ic * F0 + tid], a);
        h0[(size_t)node * F0 + tid] = a;
    }
}

// ---------------------------------------------------------------- degree
__global__ __launch_bounds__(256) void k_count(const int* __restrict__ dst,
                                               int* __restrict__ deg)
{
    int e = blockIdx.x * 256 + threadIdx.x;
    if (e < NEDGE) atomicAdd(&deg[dst[e]], 1);
}

__global__ __launch_bounds__(256) void k_dis(const int* __restrict__ deg,
                                             float* __restrict__ dis,
                                             float* __restrict__ invd)
{
    int n = blockIdx.x * 256 + threadIdx.x;
    if (n < N_NODES) {
        float d = (float)(deg[n] + 1);   // +1 self loop
        dis[n]  = rsqrtf(d);
        invd[n] = 1.f / d;
    }
}

// ---------------------------------------------------------------- h @ W (K -> 128)
__global__ __launch_bounds__(256) void k_gemm(const float* __restrict__ h,
                                              const float* __restrict__ W,
                                              float* __restrict__ out, int K)
{
    __shared__ float hs[2][F1];
    const int tid = threadIdx.x;
    const int n0  = blockIdx.x * 2;
    const int r   = tid >> 7;
    const int j   = tid & 127;

    if (tid < 2 * K) {
        int nn = (tid >= K) ? 1 : 0;
        int kk = tid - nn * K;
        hs[nn][kk] = h[(size_t)(n0 + nn) * K + kk];
    }
    __syncthreads();

    float a = 0.f;
    for (int k = 0; k < K; ++k)
        a = fmaf(hs[r][k], W[k * F1 + j], a);
    out[(size_t)(n0 + r) * F1 + j] = a;
}

// ---------------------------------------------------------------- edge aggregation (push, atomics)
__global__ __launch_bounds__(256) void k_edge(const int* __restrict__ src,
                                              const int* __restrict__ dst,
                                              const float* __restrict__ dis,
                                              const float* __restrict__ tmp,
                                              float* __restrict__ agg)
{
    int t = blockIdx.x * 256 + threadIdx.x;
    int e = t >> 7;
    int f = t & 127;
    if (e < NEDGE) {
        int s = src[e], d = dst[e];
        float nv = dis[s] * dis[d];
        atomicAdd(&agg[(size_t)d * F1 + f], tmp[(size_t)s * F1 + f] * nv);
    }
}

// ---------------------------------------------------------------- self term + bias + relu
__global__ __launch_bounds__(256) void k_finish(const float* __restrict__ agg,
                                                const float* __restrict__ tmp,
                                                const float* __restrict__ invd,
                                                const float* __restrict__ b,
                                                float* __restrict__ hout)
{
    int t = blockIdx.x * 256 + threadIdx.x;   // < N_NODES*F1
    int n = t >> 7, f = t & 127;
    float v = agg[t] + tmp[t] * invd[n] + b[f];
    hout[t] = fmaxf(v, 0.f);
}

// ---------------------------------------------------------------- mean pool per graph
__global__ __launch_bounds__(256) void k_pool(const float* __restrict__ h2,
                                              const int* __restrict__ batch,
                                              float* __restrict__ pooled,
                                              float* __restrict__ cnt)
{
    int t = blockIdx.x * 256 + threadIdx.x;   // < N_NODES*F1
    int n = t >> 7, f = t & 127;
    int g = batch[n];
    atomicAdd(&pooled[(size_t)g * F1 + f], h2[t]);
    if (f == 0) atomicAdd(&cnt[g], 1.f);
}

// ---------------------------------------------------------------- final FC 128 -> 5
__global__ __launch_bounds__(128) void k_final(const float* __restrict__ pooled,
                                               const float* __restrict__ cnt,
                                               const float* __restrict__ fc_w,
                                               const float* __restrict__ fc_b,
                                               float* __restrict__ out)
{
    __shared__ float ps[F1];
    const int g = blockIdx.x, tid = threadIdx.x;
    float inv = 1.f / fmaxf(cnt[g], 1.f);
    ps[tid] = pooled[g * F1 + tid] * inv;
    __syncthreads();
    if (tid < 5) {
        float a = fc_b[tid];
        for (int f = 0; f < F1; ++f) a = fmaf(ps[f], fc_w[f * 5 + tid], a);
        out[g * 5 + tid] = a;
    }
}

// ---------------------------------------------------------------- launch
extern "C" void kernel_launch(void* const* d_in, const int* in_sizes, int n_in,
                              void* d_out, int out_size, void* d_ws, size_t ws_size,
                              hipStream_t stream)
{
    const float* x_raw = (const float*)d_in[0];
    const float* c1w   = (const float*)d_in[1];
    const float* c1b   = (const float*)d_in[2];
    const float* c2w   = (const float*)d_in[3];
    const float* c2b   = (const float*)d_in[4];
    const float* lw    = (const float*)d_in[5];
    const float* lb    = (const float*)d_in[6];
    const float* g1w   = (const float*)d_in[7];
    const float* g1b   = (const float*)d_in[8];
    const float* g2w   = (const float*)d_in[9];
    const float* g2b   = (const float*)d_in[10];
    const float* fcw   = (const float*)d_in[11];
    const float* fcb   = (const float*)d_in[12];
    const int*   ei    = (const int*)d_in[13];
    const int*   batch = (const int*)d_in[14];
    const int* src = ei;
    const int* dst = ei + NEDGE;

    float* ws = (float*)d_ws;
    float* h0     = ws + 0;               // 786432
    float* tmp    = ws + 786432;          // 1572864
    float* agg    = ws + 2359296;         // 1572864
    float* h1     = ws + 3932160;         // 1572864
    float* h2     = ws + 5505024;         // 1572864
    float* dis    = ws + 7077888;         // 12288
    float* invd   = ws + 7090176;         // 12288
    float* pooled = ws + 7102464;         // 131072
    float* cnt    = ws + 7233536;         // 1024
    int*   deg    = (int*)(ws + 7234560); // 12288 ints

    float* out = (float*)d_out;

    hipMemsetAsync(deg, 0, N_NODES * sizeof(int), stream);
    k_encoder<<<N_NODES, 256, 0, stream>>>(x_raw, c1w, c1b, c2w, c2b, lw, lb, h0);
    k_count<<<(NEDGE + 255) / 256, 256, 0, stream>>>(dst, deg);
    k_dis<<<(N_NODES + 255) / 256, 256, 0, stream>>>(deg, dis, invd);

    // GCN layer 1
    k_gemm<<<N_NODES / 2, 256, 0, stream>>>(h0, g1w, tmp, F0);
    hipMemsetAsync(agg, 0, (size_t)N_NODES * F1 * sizeof(float), stream);
    k_edge<<<NEDGE / 2, 256, 0, stream>>>(src, dst, dis, tmp, agg);
    k_finish<<<N_NODES * F1 / 256, 256, 0, stream>>>(agg, tmp, invd, g1b, h1);

    // GCN layer 2
    k_gemm<<<N_NODES / 2, 256, 0, stream>>>(h1, g2w, tmp, F1);
    hipMemsetAsync(agg, 0, (size_t)N_NODES * F1 * sizeof(float), stream);
    k_edge<<<NEDGE / 2, 256, 0, stream>>>(src, dst, dis, tmp, agg);
    k_finish<<<N_NODES * F1 / 256, 256, 0, stream>>>(agg, tmp, invd, g2b, h2);

    // pool + fc
    hipMemsetAsync(pooled, 0, (size_t)(NGRAPH * F1 + NGRAPH) * sizeof(float), stream);
    k_pool<<<N_NODES * F1 / 256, 256, 0, stream>>>(h2, batch, pooled, cnt);
    k_final<<<NGRAPH, 128, 0, stream>>>(pooled, cnt, fcw, fcb, out);
}

// Round 6
// 504.146 us; speedup vs baseline: 1.2747x; 1.2747x over previous
//
#include <hip/hip_runtime.h>
#include <cstddef>

#define N_NODES 12288
#define SIG     2048
#define C1N     16
#define L1N     1024
#define C2N     32
#define F0      64
#define F1      128
#define NEDGE   196608
#define NGRAPH  1024

#define SLOTS   264      // c1 slots per phase (128 conv2 outputs -> 2*128+8 window)
#define C1W     272      // u16 row stride (136 words = 8 mod 32 banks -> 2-way-free B reads)

typedef float    f32x4 __attribute__((ext_vector_type(4)));
typedef _Float16 f16x8 __attribute__((ext_vector_type(8)));

__device__ __forceinline__ unsigned short f16_bits(float f) {
    union { _Float16 h; unsigned short u; } c; c.h = (_Float16)f; return c.u;
}

// ---------------------------------------------------------------- encoder
// one block (256 threads = 4 waves) per node.
// conv1: fp32 VALU, inputs straight from GLOBAL (L1/L2-hot, coalesced dwordx2
//   merges; no LDS xs => kills the round-5 stride-4 8-way bank conflicts),
//   weights register-resident (wave wv owns channels 4wv..4wv+3),
//   output -> single fp16 LDS plane (RTN via v_cvt_f16_f32).
// conv2: fp16 MFMA GEMM, K padded 16ch x 8taps = 128 (taps 5..7 zero weights
//   -> a lane's 8 k-elems are 8 CONSECUTIVE u16 slots = 4 ds_read_b32).
// mfma_f32_16x16x32_f16 (same layout family as bf16, m89/m91):
//   A row=l&15,k=(l>>4)*8+j; B col=l&15,same k; C/D col=l&15,row=(l>>4)*4+reg.
// Round-2 lesson: no min-waves hint. Round-4 lesson: q enters B address once.
// Round-5 lesson: stride-4 LDS reads are 8-way conflicts; split-bf16's extra
//   plane+mfma traffic wasn't worth 2^-17 when threshold allows fp16's 2^-12.
__global__ __launch_bounds__(256) void k_encoder(
    const float* __restrict__ x_raw,
    const float* __restrict__ conv1_w, const float* __restrict__ conv1_b,
    const float* __restrict__ conv2_w, const float* __restrict__ conv2_b,
    const float* __restrict__ lin_w,   const float* __restrict__ lin_b,
    float* __restrict__ h0)
{
    __shared__ unsigned short c1h[C1N][C1W];   // fp16 conv1 chunk
    __shared__ float wmsum[4][C2N];
    __shared__ float mean_s[C2N];

    const int tid  = threadIdx.x;
    const int node = blockIdx.x;
    const int lane = tid & 63;
    const int wv   = tid >> 6;
    const int colL = lane & 15;                // MFMA col within 16-tile
    const int hi8  = lane >> 4;                // k-subgroup / C-row-group
    const float* xrow = x_raw + (size_t)node * SIG;

    // ---- conv1 weights for this wave's 4 channels -> 32 VGPRs
    float w1r[4][8];
    #pragma unroll
    for (int icl = 0; icl < 4; ++icl) {
        const int ic = 4 * wv + icl;
        #pragma unroll
        for (int t = 0; t < 7; ++t) w1r[icl][t] = conv1_w[ic * 7 + t];
        w1r[icl][7] = conv1_b[ic];
    }

    // ---- A fragments: conv2 W in fp16, 2 m-tiles x 4 k-tiles (K=16*8=128, taps 5..7 zero)
    f16x8 wA[2][4];
    #pragma unroll
    for (int mt = 0; mt < 2; ++mt) {
        const int oc = mt * 16 + colL;
        #pragma unroll
        for (int kt = 0; kt < 4; ++kt) {
            const int ic = kt * 4 + hi8;
            #pragma unroll
            for (int j = 0; j < 8; ++j)
                wA[mt][kt][j] = (_Float16)((j < 5) ? conv2_w[oc * 80 + ic * 5 + j] : 0.f);
        }
    }
    float bias[2][4];
    #pragma unroll
    for (int mt = 0; mt < 2; ++mt)
        #pragma unroll
        for (int r = 0; r < 4; ++r)
            bias[mt][r] = conv2_b[mt * 16 + hi8 * 4 + r];

    float msumr[2][4];
    #pragma unroll
    for (int mt = 0; mt < 2; ++mt)
        #pragma unroll
        for (int r = 0; r < 4; ++r) msumr[mt][r] = 0.f;

    // ---- 4 phases of 128 conv2 output positions each
    #pragma unroll 1
    for (int phase = 0; phase < 4; ++phase) {
        const int Pb = 256 * phase - 2;        // slot s holds c1 position Pb + s

        // conv1: wave wv computes its 4 channels for slots s = lane, lane+64, ...
        for (int s = lane; s < SLOTS; s += 64) {
            const int P  = Pb + s;
            const int xb = 2 * P - 3;
            float xv[7];
            if (P >= 2 && P <= 1021) {         // interior: unguarded coalesced loads
                #pragma unroll
                for (int t = 0; t < 7; ++t) xv[t] = xrow[xb + t];
            } else {                            // boundary/pad: per-element guard
                #pragma unroll
                for (int t = 0; t < 7; ++t) {
                    int xi = xb + t;
                    xv[t] = ((unsigned)P < (unsigned)L1N && (unsigned)xi < (unsigned)SIG)
                            ? xrow[xi] : 0.f;
                }
            }
            const bool valid = (unsigned)P < (unsigned)L1N;
            #pragma unroll
            for (int icl = 0; icl < 4; ++icl) {
                float a = w1r[icl][7];
                #pragma unroll
                for (int t = 0; t < 7; ++t) a = fmaf(xv[t], w1r[icl][t], a);
                float v = valid ? fmaxf(a, 0.f) : 0.f;
                c1h[4 * wv + icl][s] = f16_bits(v);
            }
        }
        __syncthreads();

        // conv2 MFMA: wave wv covers positions 32wv..32wv+31 (nt = 0,1)
        f32x4 acc[2][2];   // [nt][mt]
        #pragma unroll
        for (int nt = 0; nt < 2; ++nt)
            #pragma unroll
            for (int mt = 0; mt < 2; ++mt) {
                acc[nt][mt][0] = bias[mt][0]; acc[nt][mt][1] = bias[mt][1];
                acc[nt][mt][2] = bias[mt][2]; acc[nt][mt][3] = bias[mt][3];
            }

        #pragma unroll
        for (int kt = 0; kt < 4; ++kt) {
            const unsigned* bp = (const unsigned*)&c1h[kt * 4 + hi8][0];
            #pragma unroll
            for (int nt = 0; nt < 2; ++nt) {
                const int q = 32 * wv + 16 * nt + colL;   // B slots 2q..2q+7
                union { unsigned u[4]; f16x8 v; } B;
                #pragma unroll
                for (int u = 0; u < 4; ++u) B.u[u] = bp[q + u];
                #pragma unroll
                for (int mt = 0; mt < 2; ++mt)
                    acc[nt][mt] = __builtin_amdgcn_mfma_f32_16x16x32_f16(wA[mt][kt], B.v, acc[nt][mt], 0, 0, 0);
            }
        }

        // relu + position-sum
        #pragma unroll
        for (int nt = 0; nt < 2; ++nt)
            #pragma unroll
            for (int mt = 0; mt < 2; ++mt)
                #pragma unroll
                for (int r = 0; r < 4; ++r)
                    msumr[mt][r] += fmaxf(acc[nt][mt][r], 0.f);

        __syncthreads();   // before next phase overwrites c1h
    }

    // ---- reduce over the 16 columns within each 16-lane group
    #pragma unroll
    for (int mt = 0; mt < 2; ++mt)
        #pragma unroll
        for (int r = 0; r < 4; ++r) {
            float s = msumr[mt][r];
            s += __shfl_xor(s, 1);
            s += __shfl_xor(s, 2);
            s += __shfl_xor(s, 4);
            s += __shfl_xor(s, 8);
            msumr[mt][r] = s;
        }
    if (colL == 0) {
        #pragma unroll
        for (int mt = 0; mt < 2; ++mt)
            #pragma unroll
            for (int r = 0; r < 4; ++r)
                wmsum[wv][mt * 16 + hi8 * 4 + r] = msumr[mt][r];
    }
    __syncthreads();

    if (tid < C2N) {
        float s = wmsum[0][tid] + wmsum[1][tid] + wmsum[2][tid] + wmsum[3][tid];
        mean_s[tid] = s * (1.f / 512.f);
    }
    __syncthreads();

    // ---- linear 32 -> 64
    if (tid < F0) {
        float a = lin_b[tid];
        #pragma unroll
        for (int ic = 0; ic < C2N; ++ic)
            a = fmaf(mean_s[ic], lin_w[ic * F0 + tid], a);
        h0[(size_t)node * F0 + tid] = a;
    }
}

// ---------------------------------------------------------------- degree
__global__ __launch_bounds__(256) void k_count(const int* __restrict__ dst,
                                               int* __restrict__ deg)
{
    int e = blockIdx.x * 256 + threadIdx.x;
    if (e < NEDGE) atomicAdd(&deg[dst[e]], 1);
}

__global__ __launch_bounds__(256) void k_dis(const int* __restrict__ deg,
                                             float* __restrict__ dis,
                                             float* __restrict__ invd)
{
    int n = blockIdx.x * 256 + threadIdx.x;
    if (n < N_NODES) {
        float d = (float)(deg[n] + 1);   // +1 self loop
        dis[n]  = rsqrtf(d);
        invd[n] = 1.f / d;
    }
}

// ---------------------------------------------------------------- h @ W (K -> 128)
__global__ __launch_bounds__(256) void k_gemm(const float* __restrict__ h,
                                              const float* __restrict__ W,
                                              float* __restrict__ out, int K)
{
    __shared__ float hs[2][F1];
    const int tid = threadIdx.x;
    const int n0  = blockIdx.x * 2;
    const int r   = tid >> 7;
    const int j   = tid & 127;

    if (tid < 2 * K) {
        int nn = (tid >= K) ? 1 : 0;
        int kk = tid - nn * K;
        hs[nn][kk] = h[(size_t)(n0 + nn) * K + kk];
    }
    __syncthreads();

    float a = 0.f;
    for (int k = 0; k < K; ++k)
        a = fmaf(hs[r][k], W[k * F1 + j], a);
    out[(size_t)(n0 + r) * F1 + j] = a;
}

// ---------------------------------------------------------------- edge aggregation (push, atomics)
__global__ __launch_bounds__(256) void k_edge(const int* __restrict__ src,
                                              const int* __restrict__ dst,
                                              const float* __restrict__ dis,
                                              const float* __restrict__ tmp,
                                              float* __restrict__ agg)
{
    int t = blockIdx.x * 256 + threadIdx.x;
    int e = t >> 7;
    int f = t & 127;
    if (e < NEDGE) {
        int s = src[e], d = dst[e];
        float nv = dis[s] * dis[d];
        atomicAdd(&agg[(size_t)d * F1 + f], tmp[(size_t)s * F1 + f] * nv);
    }
}

// ---------------------------------------------------------------- self term + bias + relu
__global__ __launch_bounds__(256) void k_finish(const float* __restrict__ agg,
                                                const float* __restrict__ tmp,
                                                const float* __restrict__ invd,
                                                const float* __restrict__ b,
                                                float* __restrict__ hout)
{
    int t = blockIdx.x * 256 + threadIdx.x;   // < N_NODES*F1
    int n = t >> 7, f = t & 127;
    float v = agg[t] + tmp[t] * invd[n] + b[f];
    hout[t] = fmaxf(v, 0.f);
}

// ---------------------------------------------------------------- mean pool per graph
__global__ __launch_bounds__(256) void k_pool(const float* __restrict__ h2,
                                              const int* __restrict__ batch,
                                              float* __restrict__ pooled,
                                              float* __restrict__ cnt)
{
    int t = blockIdx.x * 256 + threadIdx.x;   // < N_NODES*F1
    int n = t >> 7, f = t & 127;
    int g = batch[n];
    atomicAdd(&pooled[(size_t)g * F1 + f], h2[t]);
    if (f == 0) atomicAdd(&cnt[g], 1.f);
}

// ---------------------------------------------------------------- final FC 128 -> 5
__global__ __launch_bounds__(128) void k_final(const float* __restrict__ pooled,
                                               const float* __restrict__ cnt,
                                               const float* __restrict__ fc_w,
                                               const float* __restrict__ fc_b,
                                               float* __restrict__ out)
{
    __shared__ float ps[F1];
    const int g = blockIdx.x, tid = threadIdx.x;
    float inv = 1.f / fmaxf(cnt[g], 1.f);
    ps[tid] = pooled[g * F1 + tid] * inv;
    __syncthreads();
    if (tid < 5) {
        float a = fc_b[tid];
        for (int f = 0; f < F1; ++f) a = fmaf(ps[f], fc_w[f * 5 + tid], a);
        out[g * 5 + tid] = a;
    }
}

// ---------------------------------------------------------------- launch
extern "C" void kernel_launch(void* const* d_in, const int* in_sizes, int n_in,
                              void* d_out, int out_size, void* d_ws, size_t ws_size,
                              hipStream_t stream)
{
    const float* x_raw = (const float*)d_in[0];
    const float* c1w   = (const float*)d_in[1];
    const float* c1b   = (const float*)d_in[2];
    const float* c2w   = (const float*)d_in[3];
    const float* c2b   = (const float*)d_in[4];
    const float* lw    = (const float*)d_in[5];
    const float* lb    = (const float*)d_in[6];
    const float* g1w   = (const float*)d_in[7];
    const float* g1b   = (const float*)d_in[8];
    const float* g2w   = (const float*)d_in[9];
    const float* g2b   = (const float*)d_in[10];
    const float* fcw   = (const float*)d_in[11];
    const float* fcb   = (const float*)d_in[12];
    const int*   ei    = (const int*)d_in[13];
    const int*   batch = (const int*)d_in[14];
    const int* src = ei;
    const int* dst = ei + NEDGE;

    float* ws = (float*)d_ws;
    float* h0     = ws + 0;               // 786432
    float* tmp    = ws + 786432;          // 1572864
    float* agg    = ws + 2359296;         // 1572864
    float* h1     = ws + 3932160;         // 1572864
    float* h2     = ws + 5505024;         // 1572864
    float* dis    = ws + 7077888;         // 12288
    float* invd   = ws + 7090176;         // 12288
    float* pooled = ws + 7102464;         // 131072
    float* cnt    = ws + 7233536;         // 1024
    int*   deg    = (int*)(ws + 7234560); // 12288 ints

    float* out = (float*)d_out;

    hipMemsetAsync(deg, 0, N_NODES * sizeof(int), stream);
    k_encoder<<<N_NODES, 256, 0, stream>>>(x_raw, c1w, c1b, c2w, c2b, lw, lb, h0);
    k_count<<<(NEDGE + 255) / 256, 256, 0, stream>>>(dst, deg);
    k_dis<<<(N_NODES + 255) / 256, 256, 0, stream>>>(deg, dis, invd);

    // GCN layer 1
    k_gemm<<<N_NODES / 2, 256, 0, stream>>>(h0, g1w, tmp, F0);
    hipMemsetAsync(agg, 0, (size_t)N_NODES * F1 * sizeof(float), stream);
    k_edge<<<NEDGE / 2, 256, 0, stream>>>(src, dst, dis, tmp, agg);
    k_finish<<<N_NODES * F1 / 256, 256, 0, stream>>>(agg, tmp, invd, g1b, h1);

    // GCN layer 2
    k_gemm<<<N_NODES / 2, 256, 0, stream>>>(h1, g2w, tmp, F1);
    hipMemsetAsync(agg, 0, (size_t)N_NODES * F1 * sizeof(float), stream);
    k_edge<<<NEDGE / 2, 256, 0, stream>>>(src, dst, dis, tmp, agg);
    k_finish<<<N_NODES * F1 / 256, 256, 0, stream>>>(agg, tmp, invd, g2b, h2);

    // pool + fc
    hipMemsetAsync(pooled, 0, (size_t)(NGRAPH * F1 + NGRAPH) * sizeof(float), stream);
    k_pool<<<N_NODES * F1 / 256, 256, 0, stream>>>(h2, batch, pooled, cnt);
    k_final<<<NGRAPH, 128, 0, stream>>>(pooled, cnt, fcw, fcb, out);
}

// Round 7
// 300.014 us; speedup vs baseline: 2.1420x; 1.6804x over previous
//
#include <hip/hip_runtime.h>
#include <cstddef>

#define N_NODES 12288
#define SIG     2048
#define C1N     16
#define L1N     1024
#define C2N     32
#define F0      64
#define F1      128
#define NEDGE   196608
#define NGRAPH  1024

#define SLOTS   264      // c1 slots needed per phase (128 conv2 outputs)
#define C1W     274      // u16 row stride: even (b32 reads) and 4-row step = 4 banks (writes spread)
#define XW_N    1060     // words of staged x (2120 u16 >= max idx 2113)

typedef float    f32x4 __attribute__((ext_vector_type(4)));
typedef _Float16 f16x8 __attribute__((ext_vector_type(8)));

__device__ __forceinline__ unsigned short f16_bits(float f) {
    union { _Float16 h; unsigned short u; } c; c.h = (_Float16)f; return c.u;
}

// ---------------------------------------------------------------- encoder
// one block (256 threads = 4 waves) per node. BOTH convs on MFMA.
// conv1 as GEMM: C[16oc][pos] = W1[16][K=32 pad] x X[32][pos], X[k][pos]=x[2pos-3+k].
//   x staged once to LDS fp16 at +7 offset => B-frag = 8 consecutive u16, base
//   512*phase+32*tt+2*colL+8*hi8 (even) => 4 aligned ds_read_b32. Taps 7..31 have
//   zero A-weights so B garbage there is harmless. Invalid P masked in epilogue.
// conv2 as GEMM (round 6): K padded 16ch x 8taps = 128, taps 5..7 zero weights.
// mfma_f32_16x16x32_f16 (m89/m91): A row=l&15,k=(l>>4)*8+j; B col=l&15,same k;
//   C/D col=l&15, row=(l>>4)*4+reg.
// Lessons: R2 no min-waves hint; R4 q enters B addr once; R5 no stride-4 LDS reads.
__global__ __launch_bounds__(256) void k_encoder(
    const float* __restrict__ x_raw,
    const float* __restrict__ conv1_w, const float* __restrict__ conv1_b,
    const float* __restrict__ conv2_w, const float* __restrict__ conv2_b,
    const float* __restrict__ lin_w,   const float* __restrict__ lin_b,
    float* __restrict__ h0)
{
    __shared__ unsigned xw[XW_N];                    // fp16 pairs: u16[i] = x[i-7] (zero-pad)
    __shared__ __align__(16) unsigned short c1h[C1N][C1W];  // fp16 conv1 chunk
    __shared__ float wmsum[4][C2N];
    __shared__ float mean_s[C2N];

    const int tid  = threadIdx.x;
    const int node = blockIdx.x;
    const int lane = tid & 63;
    const int wv   = tid >> 6;
    const int colL = lane & 15;                // MFMA col (B/N index) / A row (M index)
    const int hi8  = lane >> 4;                // k-subgroup / C-row-group
    const float* xrow = x_raw + (size_t)node * SIG;

    // ---- stage x as fp16 (once): word w holds u16 idx 2w,2w+1 -> x[2w-7], x[2w-6]
    for (int w = tid; w < XW_N; w += 256) {
        int i0 = 2 * w - 7, i1 = 2 * w - 6;
        float a = ((unsigned)i0 < (unsigned)SIG) ? xrow[i0] : 0.f;
        float b = ((unsigned)i1 < (unsigned)SIG) ? xrow[i1] : 0.f;
        xw[w] = (unsigned)f16_bits(a) | ((unsigned)f16_bits(b) << 16);
    }

    // ---- conv1 A fragment (only hi8==0 lanes hold taps 0..6) + bias
    f16x8 w1A;
    #pragma unroll
    for (int j = 0; j < 8; ++j) w1A[j] = (_Float16)0.f;
    if (hi8 == 0) {
        #pragma unroll
        for (int j = 0; j < 7; ++j) w1A[j] = (_Float16)conv1_w[colL * 7 + j];
    }
    float bias1[4];
    #pragma unroll
    for (int r = 0; r < 4; ++r) bias1[r] = conv1_b[hi8 * 4 + r];

    // ---- conv2 A fragments, 2 m-tiles x 4 k-tiles (K=16*8=128, taps 5..7 zero)
    f16x8 wA[2][4];
    #pragma unroll
    for (int mt = 0; mt < 2; ++mt) {
        const int oc = mt * 16 + colL;
        #pragma unroll
        for (int kt = 0; kt < 4; ++kt) {
            const int ic = kt * 4 + hi8;
            #pragma unroll
            for (int j = 0; j < 8; ++j)
                wA[mt][kt][j] = (_Float16)((j < 5) ? conv2_w[oc * 80 + ic * 5 + j] : 0.f);
        }
    }
    float bias2[2][4];
    #pragma unroll
    for (int mt = 0; mt < 2; ++mt)
        #pragma unroll
        for (int r = 0; r < 4; ++r)
            bias2[mt][r] = conv2_b[mt * 16 + hi8 * 4 + r];

    float msumr[2][4];
    #pragma unroll
    for (int mt = 0; mt < 2; ++mt)
        #pragma unroll
        for (int r = 0; r < 4; ++r) msumr[mt][r] = 0.f;

    __syncthreads();   // xw ready

    // ---- 4 phases of 128 conv2 output positions (264 c1 slots) each
    #pragma unroll 1
    for (int phase = 0; phase < 4; ++phase) {
        const int Pb = 256 * phase - 2;        // slot s holds c1 position Pb + s

        // conv1 MFMA: 17 pos-tiles of 16, wave wv does tt = wv, wv+4, ...
        for (int tt = wv; tt < 17; tt += 4) {
            const int wbase = 256 * phase + 16 * tt + colL + 4 * hi8;
            union { unsigned u[4]; f16x8 v; } Bx;
            #pragma unroll
            for (int u = 0; u < 4; ++u) Bx.u[u] = xw[wbase + u];
            f32x4 a;
            a[0] = bias1[0]; a[1] = bias1[1]; a[2] = bias1[2]; a[3] = bias1[3];
            a = __builtin_amdgcn_mfma_f32_16x16x32_f16(w1A, Bx.v, a, 0, 0, 0);
            const int slot = 16 * tt + colL;
            const bool val = (unsigned)(Pb + slot) < (unsigned)L1N;
            #pragma unroll
            for (int r = 0; r < 4; ++r)
                c1h[hi8 * 4 + r][slot] = f16_bits(val ? fmaxf(a[r], 0.f) : 0.f);
        }
        __syncthreads();

        // conv2 MFMA: wave wv covers positions 32wv..32wv+31 (nt = 0,1)
        f32x4 acc[2][2];   // [nt][mt]
        #pragma unroll
        for (int nt = 0; nt < 2; ++nt)
            #pragma unroll
            for (int mt = 0; mt < 2; ++mt) {
                acc[nt][mt][0] = bias2[mt][0]; acc[nt][mt][1] = bias2[mt][1];
                acc[nt][mt][2] = bias2[mt][2]; acc[nt][mt][3] = bias2[mt][3];
            }

        #pragma unroll
        for (int kt = 0; kt < 4; ++kt) {
            const unsigned* bp = (const unsigned*)&c1h[kt * 4 + hi8][0];
            #pragma unroll
            for (int nt = 0; nt < 2; ++nt) {
                const int q = 32 * wv + 16 * nt + colL;   // B slots 2q..2q+7
                union { unsigned u[4]; f16x8 v; } B;
                #pragma unroll
                for (int u = 0; u < 4; ++u) B.u[u] = bp[q + u];
                #pragma unroll
                for (int mt = 0; mt < 2; ++mt)
                    acc[nt][mt] = __builtin_amdgcn_mfma_f32_16x16x32_f16(wA[mt][kt], B.v, acc[nt][mt], 0, 0, 0);
            }
        }

        #pragma unroll
        for (int nt = 0; nt < 2; ++nt)
            #pragma unroll
            for (int mt = 0; mt < 2; ++mt)
                #pragma unroll
                for (int r = 0; r < 4; ++r)
                    msumr[mt][r] += fmaxf(acc[nt][mt][r], 0.f);

        __syncthreads();   // before next phase overwrites c1h
    }

    // ---- reduce over the 16 columns within each 16-lane group
    #pragma unroll
    for (int mt = 0; mt < 2; ++mt)
        #pragma unroll
        for (int r = 0; r < 4; ++r) {
            float s = msumr[mt][r];
            s += __shfl_xor(s, 1);
            s += __shfl_xor(s, 2);
            s += __shfl_xor(s, 4);
            s += __shfl_xor(s, 8);
            msumr[mt][r] = s;
        }
    if (colL == 0) {
        #pragma unroll
        for (int mt = 0; mt < 2; ++mt)
            #pragma unroll
            for (int r = 0; r < 4; ++r)
                wmsum[wv][mt * 16 + hi8 * 4 + r] = msumr[mt][r];
    }
    __syncthreads();

    if (tid < C2N) {
        float s = wmsum[0][tid] + wmsum[1][tid] + wmsum[2][tid] + wmsum[3][tid];
        mean_s[tid] = s * (1.f / 512.f);
    }
    __syncthreads();

    // ---- linear 32 -> 64
    if (tid < F0) {
        float a = lin_b[tid];
        #pragma unroll
        for (int ic = 0; ic < C2N; ++ic)
            a = fmaf(mean_s[ic], lin_w[ic * F0 + tid], a);
        h0[(size_t)node * F0 + tid] = a;
    }
}

// ---------------------------------------------------------------- degree
__global__ __launch_bounds__(256) void k_count(const int* __restrict__ dst,
                                               int* __restrict__ deg)
{
    int e = blockIdx.x * 256 + threadIdx.x;
    if (e < NEDGE) atomicAdd(&deg[dst[e]], 1);
}

__global__ __launch_bounds__(256) void k_dis(const int* __restrict__ deg,
                                             float* __restrict__ dis,
                                             float* __restrict__ invd)
{
    int n = blockIdx.x * 256 + threadIdx.x;
    if (n < N_NODES) {
        float d = (float)(deg[n] + 1);   // +1 self loop
        dis[n]  = rsqrtf(d);
        invd[n] = 1.f / d;
    }
}

// ---------------------------------------------------------------- prefix scan (1 block)
__global__ __launch_bounds__(1024) void k_scan(const int* __restrict__ deg,
                                               int* __restrict__ rowptr,
                                               int* __restrict__ cursor)
{
    __shared__ int buf[1024];
    __shared__ int carry_s;
    const int t = threadIdx.x;
    if (t == 0) { carry_s = 0; rowptr[0] = 0; }
    __syncthreads();
    for (int c = 0; c < N_NODES / 1024; ++c) {
        const int i = c * 1024 + t;
        const int v = deg[i];
        buf[t] = v;
        __syncthreads();
        #pragma unroll
        for (int off = 1; off < 1024; off <<= 1) {
            int u = (t >= off) ? buf[t - off] : 0;
            __syncthreads();
            buf[t] += u;
            __syncthreads();
        }
        const int inc  = buf[t];
        const int base = carry_s;
        rowptr[i + 1] = base + inc;
        cursor[i]     = base + inc - v;
        __syncthreads();
        if (t == 1023) carry_s += inc;
        __syncthreads();
    }
}

// ---------------------------------------------------------------- CSR scatter
__global__ __launch_bounds__(256) void k_scatter(const int* __restrict__ src,
                                                 const int* __restrict__ dst,
                                                 int* __restrict__ cursor,
                                                 int* __restrict__ csr)
{
    int e = blockIdx.x * 256 + threadIdx.x;
    if (e < NEDGE) {
        int d = dst[e];
        int idx = atomicAdd(&cursor[d], 1);
        csr[idx] = src[e];
    }
}

// ---------------------------------------------------------------- h @ W (K -> 128)
__global__ __launch_bounds__(256) void k_gemm(const float* __restrict__ h,
                                              const float* __restrict__ W,
                                              float* __restrict__ out, int K)
{
    __shared__ float hs[2][F1];
    const int tid = threadIdx.x;
    const int n0  = blockIdx.x * 2;
    const int r   = tid >> 7;
    const int j   = tid & 127;

    if (tid < 2 * K) {
        int nn = (tid >= K) ? 1 : 0;
        int kk = tid - nn * K;
        hs[nn][kk] = h[(size_t)(n0 + nn) * K + kk];
    }
    __syncthreads();

    float a = 0.f;
    for (int k = 0; k < K; ++k)
        a = fmaf(hs[r][k], W[k * F1 + j], a);
    out[(size_t)(n0 + r) * F1 + j] = a;
}

// ---------------------------------------------------------------- GCN aggregation, pull (no atomics)
// fuses self-term + bias + relu; POOL variant fuses the graph mean-pool scatter.
template <int POOL>
__global__ __launch_bounds__(128) void k_pull(
    const float* __restrict__ tmp, const int* __restrict__ rowptr,
    const int* __restrict__ csr,   const float* __restrict__ dis,
    const float* __restrict__ invd, const float* __restrict__ bvec,
    float* __restrict__ hout, const int* __restrict__ batch,
    float* __restrict__ pooled)
{
    const int n = blockIdx.x;
    const int f = threadIdx.x;
    const float dn = dis[n];
    float a0 = fmaf(tmp[(size_t)n * F1 + f], invd[n], bvec[f]);  // self loop: dis[n]^2 = invd[n]
    float a1 = 0.f;
    const int e0 = rowptr[n], e1 = rowptr[n + 1];
    int e = e0;
    for (; e + 1 < e1; e += 2) {
        int s0 = csr[e], s1 = csr[e + 1];
        float w0 = dis[s0] * dn, w1 = dis[s1] * dn;
        a0 = fmaf(tmp[(size_t)s0 * F1 + f], w0, a0);
        a1 = fmaf(tmp[(size_t)s1 * F1 + f], w1, a1);
    }
    if (e < e1) {
        int s = csr[e];
        a0 = fmaf(tmp[(size_t)s * F1 + f], dis[s] * dn, a0);
    }
    float h = fmaxf(a0 + a1, 0.f);
    if (POOL) {
        atomicAdd(&pooled[(size_t)batch[n] * F1 + f], h);
    } else {
        hout[(size_t)n * F1 + f] = h;
    }
}

// ---------------------------------------------------------------- per-graph node count
__global__ __launch_bounds__(256) void k_cnt(const int* __restrict__ batch,
                                             float* __restrict__ cnt)
{
    int n = blockIdx.x * 256 + threadIdx.x;
    if (n < N_NODES) atomicAdd(&cnt[batch[n]], 1.f);
}

// ---------------------------------------------------------------- final FC 128 -> 5
__global__ __launch_bounds__(128) void k_final(const float* __restrict__ pooled,
                                               const float* __restrict__ cnt,
                                               const float* __restrict__ fc_w,
                                               const float* __restrict__ fc_b,
                                               float* __restrict__ out)
{
    __shared__ float ps[F1];
    const int g = blockIdx.x, tid = threadIdx.x;
    float inv = 1.f / fmaxf(cnt[g], 1.f);
    ps[tid] = pooled[g * F1 + tid] * inv;
    __syncthreads();
    if (tid < 5) {
        float a = fc_b[tid];
        for (int f = 0; f < F1; ++f) a = fmaf(ps[f], fc_w[f * 5 + tid], a);
        out[g * 5 + tid] = a;
    }
}

// ---------------------------------------------------------------- launch
extern "C" void kernel_launch(void* const* d_in, const int* in_sizes, int n_in,
                              void* d_out, int out_size, void* d_ws, size_t ws_size,
                              hipStream_t stream)
{
    const float* x_raw = (const float*)d_in[0];
    const float* c1w   = (const float*)d_in[1];
    const float* c1b   = (const float*)d_in[2];
    const float* c2w   = (const float*)d_in[3];
    const float* c2b   = (const float*)d_in[4];
    const float* lw    = (const float*)d_in[5];
    const float* lb    = (const float*)d_in[6];
    const float* g1w   = (const float*)d_in[7];
    const float* g1b   = (const float*)d_in[8];
    const float* g2w   = (const float*)d_in[9];
    const float* g2b   = (const float*)d_in[10];
    const float* fcw   = (const float*)d_in[11];
    const float* fcb   = (const float*)d_in[12];
    const int*   ei    = (const int*)d_in[13];
    const int*   batch = (const int*)d_in[14];
    const int* src = ei;
    const int* dst = ei + NEDGE;

    float* ws = (float*)d_ws;
    float* h0     = ws + 0;                    // 786432
    float* tmp    = ws + 786432;               // 1572864
    float* h1     = ws + 2359296;              // 1572864
    float* dis    = ws + 3932160;              // 12288
    float* invd   = ws + 3944448;              // 12288
    float* pooled = ws + 3956736;              // 131072
    float* cnt    = ws + 4087808;              // 1024
    int*   deg    = (int*)(ws + 4088832);      // 12288
    int*   rowptr = (int*)(ws + 4101120);      // 12289 (+pad)
    int*   cursor = (int*)(ws + 4113412);      // 12288
    int*   csr    = (int*)(ws + 4125700);      // 196608

    float* out = (float*)d_out;

    // ---- graph prep
    hipMemsetAsync(deg, 0, N_NODES * sizeof(int), stream);
    hipMemsetAsync(pooled, 0, (size_t)(NGRAPH * F1 + NGRAPH) * sizeof(float), stream);
    k_encoder<<<N_NODES, 256, 0, stream>>>(x_raw, c1w, c1b, c2w, c2b, lw, lb, h0);
    k_count<<<(NEDGE + 255) / 256, 256, 0, stream>>>(dst, deg);
    k_dis<<<(N_NODES + 255) / 256, 256, 0, stream>>>(deg, dis, invd);
    k_scan<<<1, 1024, 0, stream>>>(deg, rowptr, cursor);
    k_scatter<<<(NEDGE + 255) / 256, 256, 0, stream>>>(src, dst, cursor, csr);

    // GCN layer 1
    k_gemm<<<N_NODES / 2, 256, 0, stream>>>(h0, g1w, tmp, F0);
    k_pull<0><<<N_NODES, 128, 0, stream>>>(tmp, rowptr, csr, dis, invd, g1b, h1, batch, pooled);

    // GCN layer 2 (fused pool)
    k_gemm<<<N_NODES / 2, 256, 0, stream>>>(h1, g2w, tmp, F1);
    k_pull<1><<<N_NODES, 128, 0, stream>>>(tmp, rowptr, csr, dis, invd, g2b, nullptr, batch, pooled);

    // pool denom + fc
    k_cnt<<<(N_NODES + 255) / 256, 256, 0, stream>>>(batch, cnt);
    k_final<<<NGRAPH, 128, 0, stream>>>(pooled, cnt, fcw, fcb, out);
}

// Round 8
// 217.876 us; speedup vs baseline: 2.9495x; 1.3770x over previous
//
#include <hip/hip_runtime.h>
#include <cstddef>

#define N_NODES 12288
#define SIG     2048
#define C1N     16
#define L1N     1024
#define C2N     32
#define F0      64
#define F1      128
#define NEDGE   196608
#define NGRAPH  1024

#define C1S     1042     // u16 row stride of full c1 buffer (even; 2084B = 521 words)
#define XW_N    1044     // u32 words of staged x: u16 idx i = x[i-8]

typedef float    f32x4 __attribute__((ext_vector_type(4)));
typedef _Float16 f16x8 __attribute__((ext_vector_type(8)));

__device__ __forceinline__ unsigned short f16_bits(float f) {
    union { _Float16 h; unsigned short u; } c; c.h = (_Float16)f; return c.u;
}
__device__ __forceinline__ unsigned f16_pk(float a, float b) {
    return (unsigned)f16_bits(a) | ((unsigned)f16_bits(b) << 16);
}

// ---------------------------------------------------------------- encoder
// one block (256 threads = 4 waves) per node. BOTH convs on MFMA, full-row c1:
// only 2 hot barriers (after x-stage, after conv1) instead of 8 phase barriers.
// conv1 as GEMM: C[16oc][1024pos] = W1[16][K=32] x X, X[k][pos]=x[2pos-4+k],
//   weights at k=1..7 (tap k-1; k=0 zero) so the LDS base index stays even.
//   x staged once as fp16 pairs: xw word w = {x[2w-8], x[2w-7]} -> B-frag =
//   4 aligned ds_read_b32 at word 16T+colL+4hi8+2. All 1024 pos valid: no mask.
// conv2 as GEMM: K padded 16ch x 8taps = 128 (taps 5..7 zero weights); B-frag =
//   8 consecutive u16 of row ic at word ic*521 + q (q = position).
// mfma_f32_16x16x32_f16 (m89/m91): A row=l&15,k=(l>>4)*8+j; B col=l&15,same k;
//   C/D col=l&15, row=(l>>4)*4+reg.
// Lessons: R2 no min-waves hint; R4 q enters B addr once; R5 no stride-4 reads;
//   R7 per-phase barriers were the latency floor.
__global__ __launch_bounds__(256) void k_encoder(
    const float* __restrict__ x_raw,
    const float* __restrict__ conv1_w, const float* __restrict__ conv1_b,
    const float* __restrict__ conv2_w, const float* __restrict__ conv2_b,
    const float* __restrict__ lin_w,   const float* __restrict__ lin_b,
    float* __restrict__ h0)
{
    __shared__ __align__(16) unsigned xw[XW_N];              // fp16-pair staged x
    __shared__ __align__(16) unsigned short c1h[C1N][C1S];   // fp16 conv1, s = pos+2
    __shared__ float wmsum[4][C2N];
    __shared__ float mean_s[C2N];

    const int tid  = threadIdx.x;
    const int node = blockIdx.x;
    const int lane = tid & 63;
    const int wv   = tid >> 6;
    const int colL = lane & 15;
    const int hi8  = lane >> 4;
    const float* xrow = x_raw + (size_t)node * SIG;

    // ---- stage x as fp16 pairs: thread t covers x[8t..8t+7] -> words 4t+4..4t+7
    {
        float4 xa = ((const float4*)xrow)[2 * tid];
        float4 xb = ((const float4*)xrow)[2 * tid + 1];
        uint4 w;
        w.x = f16_pk(xa.x, xa.y); w.y = f16_pk(xa.z, xa.w);
        w.z = f16_pk(xb.x, xb.y); w.w = f16_pk(xb.z, xb.w);
        *(uint4*)&xw[4 * tid + 4] = w;
    }
    if (tid < 4)  xw[tid] = 0u;            // x[-8..-1]
    if (tid < 16) xw[1028 + tid] = 0u;     // x[2048..] pad
    // zero c1 pads: s in {0,1} (pos -2,-1) and {1026..1031} (pos >= 1024)
    if (tid < 128) {
        int row = tid >> 3, o = tid & 7;
        int s = (o < 2) ? o : 1024 + o;
        c1h[row][s] = 0;
    }

    // ---- conv1 A fragment: k=1..7 hold taps 0..6 (hi8==0 lanes only)
    f16x8 w1A;
    #pragma unroll
    for (int j = 0; j < 8; ++j) w1A[j] = (_Float16)0.f;
    if (hi8 == 0) {
        #pragma unroll
        for (int j = 1; j < 8; ++j) w1A[j] = (_Float16)conv1_w[colL * 7 + (j - 1)];
    }
    float bias1[4];
    #pragma unroll
    for (int r = 0; r < 4; ++r) bias1[r] = conv1_b[hi8 * 4 + r];

    // ---- conv2 A fragments, 2 m-tiles x 4 k-tiles (K=16*8=128, taps 5..7 zero)
    f16x8 wA[2][4];
    #pragma unroll
    for (int mt = 0; mt < 2; ++mt) {
        const int oc = mt * 16 + colL;
        #pragma unroll
        for (int kt = 0; kt < 4; ++kt) {
            const int ic = kt * 4 + hi8;
            #pragma unroll
            for (int j = 0; j < 8; ++j)
                wA[mt][kt][j] = (_Float16)((j < 5) ? conv2_w[oc * 80 + ic * 5 + j] : 0.f);
        }
    }
    float bias2[2][4];
    #pragma unroll
    for (int mt = 0; mt < 2; ++mt)
        #pragma unroll
        for (int r = 0; r < 4; ++r)
            bias2[mt][r] = conv2_b[mt * 16 + hi8 * 4 + r];

    __syncthreads();   // xw + c1 pads ready

    // ---- conv1: 64 pos-tiles of 16; wave wv does T = wv, wv+4, ...
    for (int i = 0; i < 16; ++i) {
        const int T = wv + 4 * i;
        const int pos   = 16 * T + colL;
        const int wbase = 16 * T + colL + 4 * hi8 + 2;
        union { unsigned u[4]; f16x8 v; } Bx;
        #pragma unroll
        for (int u = 0; u < 4; ++u) Bx.u[u] = xw[wbase + u];
        f32x4 a;
        a[0] = bias1[0]; a[1] = bias1[1]; a[2] = bias1[2]; a[3] = bias1[3];
        a = __builtin_amdgcn_mfma_f32_16x16x32_f16(w1A, Bx.v, a, 0, 0, 0);
        #pragma unroll
        for (int r = 0; r < 4; ++r)
            c1h[hi8 * 4 + r][pos + 2] = f16_bits(fmaxf(a[r], 0.f));
    }
    __syncthreads();   // c1 ready

    // ---- conv2: wave wv covers positions 128wv..128wv+127 (8 n-tiles, chunks of 2)
    float msumr[2][4];
    #pragma unroll
    for (int mt = 0; mt < 2; ++mt)
        #pragma unroll
        for (int r = 0; r < 4; ++r) msumr[mt][r] = 0.f;

    #pragma unroll 1
    for (int nt2 = 0; nt2 < 4; ++nt2) {
        f32x4 acc[2][2];   // [ntl][mt]
        #pragma unroll
        for (int ntl = 0; ntl < 2; ++ntl)
            #pragma unroll
            for (int mt = 0; mt < 2; ++mt) {
                acc[ntl][mt][0] = bias2[mt][0]; acc[ntl][mt][1] = bias2[mt][1];
                acc[ntl][mt][2] = bias2[mt][2]; acc[ntl][mt][3] = bias2[mt][3];
            }
        #pragma unroll
        for (int kt = 0; kt < 4; ++kt) {
            const unsigned* bp = (const unsigned*)&c1h[4 * kt + hi8][0];
            #pragma unroll
            for (int ntl = 0; ntl < 2; ++ntl) {
                const int q = 128 * wv + 16 * (2 * nt2 + ntl) + colL;
                union { unsigned u[4]; f16x8 v; } B;
                #pragma unroll
                for (int u = 0; u < 4; ++u) B.u[u] = bp[q + u];
                #pragma unroll
                for (int mt = 0; mt < 2; ++mt)
                    acc[ntl][mt] = __builtin_amdgcn_mfma_f32_16x16x32_f16(wA[mt][kt], B.v, acc[ntl][mt], 0, 0, 0);
            }
        }
        #pragma unroll
        for (int ntl = 0; ntl < 2; ++ntl)
            #pragma unroll
            for (int mt = 0; mt < 2; ++mt)
                #pragma unroll
                for (int r = 0; r < 4; ++r)
                    msumr[mt][r] += fmaxf(acc[ntl][mt][r], 0.f);
    }

    // ---- reduce over the 16 columns within each 16-lane group
    #pragma unroll
    for (int mt = 0; mt < 2; ++mt)
        #pragma unroll
        for (int r = 0; r < 4; ++r) {
            float s = msumr[mt][r];
            s += __shfl_xor(s, 1);
            s += __shfl_xor(s, 2);
            s += __shfl_xor(s, 4);
            s += __shfl_xor(s, 8);
            msumr[mt][r] = s;
        }
    if (colL == 0) {
        #pragma unroll
        for (int mt = 0; mt < 2; ++mt)
            #pragma unroll
            for (int r = 0; r < 4; ++r)
                wmsum[wv][mt * 16 + hi8 * 4 + r] = msumr[mt][r];
    }
    __syncthreads();

    if (tid < C2N) {
        float s = wmsum[0][tid] + wmsum[1][tid] + wmsum[2][tid] + wmsum[3][tid];
        mean_s[tid] = s * (1.f / 512.f);
    }
    __syncthreads();

    // ---- linear 32 -> 64
    if (tid < F0) {
        float a = lin_b[tid];
        #pragma unroll
        for (int ic = 0; ic < C2N; ++ic)
            a = fmaf(mean_s[ic], lin_w[ic * F0 + tid], a);
        h0[(size_t)node * F0 + tid] = a;
    }
}

// ---------------------------------------------------------------- degree + graph-node count (fused)
__global__ __launch_bounds__(256) void k_count_cnt(const int* __restrict__ dst,
                                                   const int* __restrict__ batch,
                                                   int* __restrict__ deg,
                                                   float* __restrict__ cnt)
{
    const int bid = blockIdx.x;
    if (bid < NEDGE / 256) {
        int e = bid * 256 + threadIdx.x;
        atomicAdd(&deg[dst[e]], 1);
    } else {
        int n = (bid - NEDGE / 256) * 256 + threadIdx.x;
        atomicAdd(&cnt[batch[n]], 1.f);
    }
}

// ---------------------------------------------------------------- scan + dis/invd (fused, 1 block)
__global__ __launch_bounds__(1024) void k_scan(const int* __restrict__ deg,
                                               int* __restrict__ rowptr,
                                               int* __restrict__ cursor,
                                               float* __restrict__ dis,
                                               float* __restrict__ invd)
{
    __shared__ int buf[1024];
    const int t = threadIdx.x;
    int d[12]; int s = 0;
    #pragma unroll
    for (int m = 0; m < 12; ++m) { d[m] = deg[12 * t + m]; s += d[m]; }
    buf[t] = s;
    __syncthreads();
    for (int off = 1; off < 1024; off <<= 1) {
        int u = (t >= off) ? buf[t - off] : 0;
        __syncthreads();
        buf[t] += u;
        __syncthreads();
    }
    if (t == 0) rowptr[0] = 0;
    int run = buf[t] - s;                   // exclusive prefix
    #pragma unroll
    for (int m = 0; m < 12; ++m) {
        const int i = 12 * t + m;
        cursor[i] = run;
        run += d[m];
        rowptr[i + 1] = run;
        float df = (float)(d[m] + 1);
        dis[i]  = rsqrtf(df);
        invd[i] = 1.f / df;
    }
}

// ---------------------------------------------------------------- CSR scatter
__global__ __launch_bounds__(256) void k_scatter(const int* __restrict__ src,
                                                 const int* __restrict__ dst,
                                                 int* __restrict__ cursor,
                                                 int* __restrict__ csr)
{
    int e = blockIdx.x * 256 + threadIdx.x;
    if (e < NEDGE) {
        int d = dst[e];
        int idx = atomicAdd(&cursor[d], 1);
        csr[idx] = src[e];
    }
}

// ---------------------------------------------------------------- aggregation BEFORE transform (pull)
// agg[n] = invd[n]*h[n] + sum_s dis[s]*dis[n]*h[s]   (linearity of GCN: agg then @W)
template <int F>
__global__ __launch_bounds__(256) void k_pull_a(
    const float* __restrict__ h, const int* __restrict__ rowptr,
    const int* __restrict__ csr, const float* __restrict__ dis,
    const float* __restrict__ invd, float* __restrict__ agg)
{
    const int npb = 256 / F;
    const int n = blockIdx.x * npb + threadIdx.x / F;
    const int f = threadIdx.x & (F - 1);
    const float dn = dis[n];
    float a0 = h[(size_t)n * F + f] * invd[n];
    float a1 = 0.f, a2 = 0.f, a3 = 0.f;
    int e = rowptr[n];
    const int e1 = rowptr[n + 1];
    for (; e + 3 < e1; e += 4) {
        int s0 = csr[e], s1 = csr[e + 1], s2 = csr[e + 2], s3 = csr[e + 3];
        a0 = fmaf(h[(size_t)s0 * F + f], dis[s0] * dn, a0);
        a1 = fmaf(h[(size_t)s1 * F + f], dis[s1] * dn, a1);
        a2 = fmaf(h[(size_t)s2 * F + f], dis[s2] * dn, a2);
        a3 = fmaf(h[(size_t)s3 * F + f], dis[s3] * dn, a3);
    }
    for (; e < e1; ++e) {
        int s0 = csr[e];
        a0 = fmaf(h[(size_t)s0 * F + f], dis[s0] * dn, a0);
    }
    agg[(size_t)n * F + f] = (a0 + a1) + (a2 + a3);
}

// ---------------------------------------------------------------- agg @ W + bias + relu (+pool)
// 8 nodes per block; thread (half=tid>>7, j=tid&127) computes nodes half*4..half*4+3.
template <int K, int POOL>
__global__ __launch_bounds__(256) void k_gemm_f(
    const float* __restrict__ in, const float* __restrict__ W,
    const float* __restrict__ bvec, float* __restrict__ out,
    const int* __restrict__ batch, float* __restrict__ pooled)
{
    __shared__ float hs[8][K];
    const int tid  = threadIdx.x;
    const int n0   = blockIdx.x * 8;
    const int j    = tid & 127;
    const int half = tid >> 7;

    #pragma unroll
    for (int it = 0; it < 8 * K / 256; ++it) {
        int idx = it * 256 + tid;
        int nn = idx / K, kk = idx & (K - 1);
        hs[nn][kk] = in[(size_t)(n0 + nn) * K + kk];
    }
    __syncthreads();

    float a[4];
    #pragma unroll
    for (int c = 0; c < 4; ++c) a[c] = bvec[j];

    for (int k4 = 0; k4 < K; k4 += 4) {
        float w0 = W[(k4 + 0) * F1 + j];
        float w1 = W[(k4 + 1) * F1 + j];
        float w2 = W[(k4 + 2) * F1 + j];
        float w3 = W[(k4 + 3) * F1 + j];
        #pragma unroll
        for (int c = 0; c < 4; ++c) {
            float4 hv = *(const float4*)&hs[half * 4 + c][k4];   // uniform b128
            a[c] = fmaf(hv.x, w0, a[c]);
            a[c] = fmaf(hv.y, w1, a[c]);
            a[c] = fmaf(hv.z, w2, a[c]);
            a[c] = fmaf(hv.w, w3, a[c]);
        }
    }
    #pragma unroll
    for (int c = 0; c < 4; ++c) {
        float r = fmaxf(a[c], 0.f);
        int n = n0 + half * 4 + c;
        if (POOL) atomicAdd(&pooled[(size_t)batch[n] * F1 + j], r);
        else      out[(size_t)n * F1 + j] = r;
    }
}

// ---------------------------------------------------------------- final FC 128 -> 5
__global__ __launch_bounds__(128) void k_final(const float* __restrict__ pooled,
                                               const float* __restrict__ cnt,
                                               const float* __restrict__ fc_w,
                                               const float* __restrict__ fc_b,
                                               float* __restrict__ out)
{
    __shared__ float ps[F1];
    const int g = blockIdx.x, tid = threadIdx.x;
    float inv = 1.f / fmaxf(cnt[g], 1.f);
    ps[tid] = pooled[g * F1 + tid] * inv;
    __syncthreads();
    if (tid < 5) {
        float a = fc_b[tid];
        for (int f = 0; f < F1; ++f) a = fmaf(ps[f], fc_w[f * 5 + tid], a);
        out[g * 5 + tid] = a;
    }
}

// ---------------------------------------------------------------- launch
extern "C" void kernel_launch(void* const* d_in, const int* in_sizes, int n_in,
                              void* d_out, int out_size, void* d_ws, size_t ws_size,
                              hipStream_t stream)
{
    const float* x_raw = (const float*)d_in[0];
    const float* c1w   = (const float*)d_in[1];
    const float* c1b   = (const float*)d_in[2];
    const float* c2w   = (const float*)d_in[3];
    const float* c2b   = (const float*)d_in[4];
    const float* lw    = (const float*)d_in[5];
    const float* lb    = (const float*)d_in[6];
    const float* g1w   = (const float*)d_in[7];
    const float* g1b   = (const float*)d_in[8];
    const float* g2w   = (const float*)d_in[9];
    const float* g2b   = (const float*)d_in[10];
    const float* fcw   = (const float*)d_in[11];
    const float* fcb   = (const float*)d_in[12];
    const int*   ei    = (const int*)d_in[13];
    const int*   batch = (const int*)d_in[14];
    const int* src = ei;
    const int* dst = ei + NEDGE;

    float* ws = (float*)d_ws;
    float* h0     = ws + 0;                    // 786432  (12288 x 64)
    float* agg1   = ws + 786432;               // 786432  (12288 x 64)
    float* h1     = ws + 1572864;              // 1572864 (12288 x 128)
    float* agg2   = ws + 3145728;              // 1572864 (12288 x 128)
    float* dis    = ws + 4718592;              // 12288
    float* invd   = ws + 4730880;              // 12288
    float* pooled = ws + 4743168;              // 131072
    float* cnt    = ws + 4874240;              // 1024
    int*   deg    = (int*)(ws + 4875264);      // 12288
    int*   rowptr = (int*)(ws + 4887552);      // 12289 (+pad)
    int*   cursor = (int*)(ws + 4899844);      // 12288
    int*   csr    = (int*)(ws + 4912132);      // 196608

    float* out = (float*)d_out;

    hipMemsetAsync(deg, 0, N_NODES * sizeof(int), stream);
    hipMemsetAsync(pooled, 0, (size_t)(NGRAPH * F1 + NGRAPH) * sizeof(float), stream);

    k_encoder<<<N_NODES, 256, 0, stream>>>(x_raw, c1w, c1b, c2w, c2b, lw, lb, h0);
    k_count_cnt<<<NEDGE / 256 + N_NODES / 256, 256, 0, stream>>>(dst, batch, deg, cnt);
    k_scan<<<1, 1024, 0, stream>>>(deg, rowptr, cursor, dis, invd);
    k_scatter<<<NEDGE / 256, 256, 0, stream>>>(src, dst, cursor, csr);

    // GCN layer 1: aggregate (64-dim) then transform
    k_pull_a<F0><<<N_NODES / 4, 256, 0, stream>>>(h0, rowptr, csr, dis, invd, agg1);
    k_gemm_f<F0, 0><<<N_NODES / 8, 256, 0, stream>>>(agg1, g1w, g1b, h1, batch, pooled);

    // GCN layer 2: aggregate (128-dim) then transform + fused pool
    k_pull_a<F1><<<N_NODES / 2, 256, 0, stream>>>(h1, rowptr, csr, dis, invd, agg2);
    k_gemm_f<F1, 1><<<N_NODES / 8, 256, 0, stream>>>(agg2, g2w, g2b, nullptr, batch, pooled);

    k_final<<<NGRAPH, 128, 0, stream>>>(pooled, cnt, fcw, fcb, out);
}